// Round 1
// baseline (2379.588 us; speedup 1.0000x reference)
//
#include <hip/hip_runtime.h>
#include <hip/hip_bf16.h>

#define DD 128
#define HH 128
#define WW 128
#define VOX (DD * HH * WW)  // 2097152

typedef unsigned short u16;

__device__ __forceinline__ float bf2f(u16 h) {
    return __uint_as_float(((unsigned int)h) << 16);
}

__device__ __forceinline__ u16 f2bf(float f) {
    unsigned int u = __float_as_uint(f);
    return (u16)((u + 0x7FFF + ((u >> 16) & 1)) >> 16);  // RNE
}

// w2 [16][8][27] (OI·taps) -> w2t [(ic*27+tap)*16 + oc]
__global__ __launch_bounds__(256) void transpose_w2_kernel(
    const float* __restrict__ w2, float* __restrict__ w2t) {
    int i = blockIdx.x * 256 + threadIdx.x;
    if (i < 3456) {
        int oc = i / 216;
        int r = i % 216;  // ic*27+tap
        w2t[r * 16 + oc] = w2[i];
    }
}

// conv1: in [D,H,W] fp32 (one batch), field fused, relu, out bf16 [8][VOX]
__global__ __launch_bounds__(256) void conv1_kernel(
    const float* __restrict__ in, const float* __restrict__ w1,
    const float* __restrict__ b1, u16* __restrict__ x1) {
    __shared__ float table[384];
    for (int s = threadIdx.x; s < 384; s += 256)
        table[s] = 1.0f + 0.1f * sinf(6.283185307179586f * (float)s / 384.0f);
    __syncthreads();

    const int w = threadIdx.x & 127;
    const int h = (blockIdx.x << 1) | (threadIdx.x >> 7);
    const int d = blockIdx.y;

    float acc[8];
#pragma unroll
    for (int oc = 0; oc < 8; ++oc) acc[oc] = b1[oc];

#pragma unroll
    for (int dz = 0; dz < 3; ++dz) {
        const int zz = d + dz - 1;
        const bool zok = (unsigned)zz < DD;
#pragma unroll
        for (int dy = 0; dy < 3; ++dy) {
            const int yy = h + dy - 1;
            const bool yok = zok && ((unsigned)yy < HH);
            const int rowbase = (zz * HH + yy) * WW;
            const int sbase = zz + yy;
#pragma unroll
            for (int dx = 0; dx < 3; ++dx) {
                const int xx = w + dx - 1;
                float v = 0.0f;
                if (yok && ((unsigned)xx < WW))
                    v = in[rowbase + xx] * table[sbase + xx];
                const int tap = dz * 9 + dy * 3 + dx;
#pragma unroll
                for (int oc = 0; oc < 8; ++oc)
                    acc[oc] = fmaf(w1[oc * 27 + tap], v, acc[oc]);
            }
        }
    }
    const int voxel = (d * HH + h) * WW + w;
#pragma unroll
    for (int oc = 0; oc < 8; ++oc) {
        float r = acc[oc] > 0.0f ? acc[oc] : 0.0f;
        x1[oc * VOX + voxel] = f2bf(r);
    }
}

// conv2: x1 bf16 [8][VOX] -> x2 bf16 [16][VOX], relu
// w2t layout [(ic*27+tap)*16 + oc] -> 16 contiguous uniform weights per tap
__global__ __launch_bounds__(256) void conv2_kernel(
    const u16* __restrict__ x1, const float* __restrict__ w2t,
    const float* __restrict__ b2, u16* __restrict__ x2) {
    const int w = threadIdx.x & 127;
    const int h = (blockIdx.x << 1) | (threadIdx.x >> 7);
    const int d = blockIdx.y;

    float acc[16];
#pragma unroll
    for (int oc = 0; oc < 16; ++oc) acc[oc] = b2[oc];

#pragma unroll 1
    for (int ic = 0; ic < 8; ++ic) {
        const u16* base = x1 + ic * VOX;
        const float* wic = w2t + ic * 27 * 16;
#pragma unroll
        for (int dz = 0; dz < 3; ++dz) {
            const int zz = d + dz - 1;
            const bool zok = (unsigned)zz < DD;
#pragma unroll
            for (int dy = 0; dy < 3; ++dy) {
                const int yy = h + dy - 1;
                const bool yok = zok && ((unsigned)yy < HH);
                const int rowbase = (zz * HH + yy) * WW;
#pragma unroll
                for (int dx = 0; dx < 3; ++dx) {
                    const int xx = w + dx - 1;
                    float v = 0.0f;
                    if (yok && ((unsigned)xx < WW)) v = bf2f(base[rowbase + xx]);
                    const float* wp = wic + (dz * 9 + dy * 3 + dx) * 16;
#pragma unroll
                    for (int oc = 0; oc < 16; ++oc)
                        acc[oc] = fmaf(wp[oc], v, acc[oc]);
                }
            }
        }
    }
    const int voxel = (d * HH + h) * WW + w;
#pragma unroll
    for (int oc = 0; oc < 16; ++oc) {
        float r = acc[oc] > 0.0f ? acc[oc] : 0.0f;
        x2[oc * VOX + voxel] = f2bf(r);
    }
}

// conv3: x2 bf16 [16][VOX] -> out fp32 [VOX] (one batch), tanh
// w3 natural layout [ic*27+tap] is already contiguous-uniform
__global__ __launch_bounds__(256) void conv3_kernel(
    const u16* __restrict__ x2, const float* __restrict__ w3,
    const float* __restrict__ b3, float* __restrict__ out) {
    const int w = threadIdx.x & 127;
    const int h = (blockIdx.x << 1) | (threadIdx.x >> 7);
    const int d = blockIdx.y;

    float acc = b3[0];
#pragma unroll 1
    for (int ic = 0; ic < 16; ++ic) {
        const u16* base = x2 + ic * VOX;
        const float* wic = w3 + ic * 27;
#pragma unroll
        for (int dz = 0; dz < 3; ++dz) {
            const int zz = d + dz - 1;
            const bool zok = (unsigned)zz < DD;
#pragma unroll
            for (int dy = 0; dy < 3; ++dy) {
                const int yy = h + dy - 1;
                const bool yok = zok && ((unsigned)yy < HH);
                const int rowbase = (zz * HH + yy) * WW;
#pragma unroll
                for (int dx = 0; dx < 3; ++dx) {
                    const int xx = w + dx - 1;
                    float v = 0.0f;
                    if (yok && ((unsigned)xx < WW)) v = bf2f(base[rowbase + xx]);
                    acc = fmaf(wic[dz * 9 + dy * 3 + dx], v, acc);
                }
            }
        }
    }
    const int voxel = (d * HH + h) * WW + w;
    out[voxel] = tanhf(acc);
}

extern "C" void kernel_launch(void* const* d_in, const int* in_sizes, int n_in,
                              void* d_out, int out_size, void* d_ws, size_t ws_size,
                              hipStream_t stream) {
    const float* cube = (const float*)d_in[0];
    const float* w1 = (const float*)d_in[1];
    const float* b1 = (const float*)d_in[2];
    const float* w2 = (const float*)d_in[3];
    const float* b2 = (const float*)d_in[4];
    const float* w3 = (const float*)d_in[5];
    const float* b3 = (const float*)d_in[6];
    float* out = (float*)d_out;

    // ws layout: w2t (16 KiB) | x1 bf16 8*VOX (32 MiB) | x2 bf16 16*VOX (64 MiB)
    char* ws = (char*)d_ws;
    float* w2t = (float*)ws;
    u16* x1 = (u16*)(ws + 16384);
    u16* x2 = (u16*)(ws + 16384 + (size_t)8 * VOX * sizeof(u16));

    transpose_w2_kernel<<<dim3(14), dim3(256), 0, stream>>>(w2, w2t);

    dim3 grid(HH / 2, DD);
    for (int b = 0; b < 2; ++b) {
        conv1_kernel<<<grid, dim3(256), 0, stream>>>(cube + (size_t)b * VOX, w1, b1, x1);
        conv2_kernel<<<grid, dim3(256), 0, stream>>>(x1, w2t, b2, x2);
        conv3_kernel<<<grid, dim3(256), 0, stream>>>(x2, w3, b3, out + (size_t)b * VOX);
    }
}

// Round 2
// 413.531 us; speedup vs baseline: 5.7543x; 5.7543x over previous
//
#include <hip/hip_runtime.h>
#include <hip/hip_bf16.h>

#define DD 128
#define HH 128
#define WW 128
#define VOX (DD * HH * WW)  // 2097152

typedef unsigned short u16;
typedef __attribute__((ext_vector_type(8))) short bf16x8;
typedef __attribute__((ext_vector_type(4))) float f32x4;

__device__ __forceinline__ float bf2f(u16 h) {
    return __uint_as_float(((unsigned int)h) << 16);
}
__device__ __forceinline__ u16 f2bf(float f) {
    unsigned int u = __float_as_uint(f);
    return (u16)((u + 0x7FFF + ((u >> 16) & 1)) >> 16);  // RNE
}
// packed bf16 extraction from a dword holding [ic even | ic odd]
__device__ __forceinline__ float blo(unsigned u) { return __uint_as_float(u << 16); }
__device__ __forceinline__ float bhi(unsigned u) { return __uint_as_float(u & 0xffff0000u); }
__device__ __forceinline__ unsigned pk2(float a, float b) {
    float ra = a > 0.f ? a : 0.f, rb = b > 0.f ? b : 0.f;
    return (unsigned)f2bf(ra) | ((unsigned)f2bf(rb) << 16);
}

// prep: build B-fragments for conv2 MFMA, w3 transpose, zero page.
// w2frag[(s*64+lane)*8 + j] = bf16(w2[oc=lane&15][ic=j][tap=s*4+(lane>>4)]), 0 if tap>26
// w3t[tap*16+ic] = w3[ic*27+tap]
__global__ __launch_bounds__(256) void prep_kernel(
    const float* __restrict__ w2, const float* __restrict__ w3,
    u16* __restrict__ w2frag, float* __restrict__ w3t, u16* __restrict__ zeropage) {
    int i = blockIdx.x * 256 + threadIdx.x;
    if (i < 3584) {
        int j = i & 7, l = (i >> 3) & 63, s = i >> 9;
        int tap = s * 4 + (l >> 4), oc = l & 15, ic = j;
        float v = (tap < 27) ? w2[(oc * 8 + ic) * 27 + tap] : 0.0f;
        w2frag[i] = f2bf(v);
    }
    if (i < 432) {
        int tap = i >> 4, ic = i & 15;
        w3t[i] = w3[ic * 27 + tap];
    }
    if (i < 32) zeropage[i] = 0;
}

// conv1: in [D,H,W] fp32 (one batch), field fused, relu, out bf16 channels-last [VOX][8]
__global__ __launch_bounds__(256) void conv1_kernel(
    const float* __restrict__ in, const float* __restrict__ w1,
    const float* __restrict__ b1, u16* __restrict__ x1) {
    __shared__ float table[384];
    for (int s = threadIdx.x; s < 384; s += 256)
        table[s] = 1.0f + 0.1f * sinf(6.283185307179586f * (float)s / 384.0f);
    __syncthreads();

    const int w = threadIdx.x & 127;
    const int h = (blockIdx.x << 1) | (threadIdx.x >> 7);
    const int d = blockIdx.y;

    float acc[8];
#pragma unroll
    for (int oc = 0; oc < 8; ++oc) acc[oc] = b1[oc];

#pragma unroll
    for (int dz = 0; dz < 3; ++dz) {
        const int zz = d + dz - 1;
        const bool zok = (unsigned)zz < DD;
#pragma unroll
        for (int dy = 0; dy < 3; ++dy) {
            const int yy = h + dy - 1;
            const bool yok = zok && ((unsigned)yy < HH);
            const int rowbase = (zz * HH + yy) * WW;
            const int sbase = zz + yy;
#pragma unroll
            for (int dx = 0; dx < 3; ++dx) {
                const int xx = w + dx - 1;
                float v = 0.0f;
                if (yok && ((unsigned)xx < WW))
                    v = in[rowbase + xx] * table[sbase + xx];
                const int tap = dz * 9 + dy * 3 + dx;
#pragma unroll
                for (int oc = 0; oc < 8; ++oc)
                    acc[oc] = fmaf(w1[oc * 27 + tap], v, acc[oc]);
            }
        }
    }
    const size_t voxel = (size_t)(d * HH + h) * WW + w;
    uint4 o;
    o.x = pk2(acc[0], acc[1]);
    o.y = pk2(acc[2], acc[3]);
    o.z = pk2(acc[4], acc[5]);
    o.w = pk2(acc[6], acc[7]);
    *(uint4*)(x1 + voxel * 8) = o;
}

// conv2: implicit-GEMM MFMA. x1 channels-last [VOX][8] bf16 -> x2 channels-last [VOX][16] bf16.
// GEMM: C[M=voxels][N=16oc] = A[M][K=216] * B[K][16], k = tap*8 + ic (tap-major).
// Wave tile: M=16 consecutive voxels along w. 7 K-steps of mfma_f32_16x16x32_bf16.
// A-frag: lane(q=lane>>4, mi=lane&15) step s -> tap=4s+q, 8 ic = one 16B load.
__global__ __launch_bounds__(256) void conv2_mfma_kernel(
    const u16* __restrict__ x1, const u16* __restrict__ w2frag,
    const float* __restrict__ b2, u16* __restrict__ x2,
    const u16* __restrict__ zeropage) {
    const int lane = threadIdx.x & 63;
    const int wv = threadIdx.x >> 6;
    const int q = lane >> 4;
    const int mi = lane & 15;

    const int v0 = blockIdx.x * 64 + wv * 16;  // wave's first voxel (within one w-row)
    const int w0 = v0 & 127;
    const int h0 = (v0 >> 7) & 127;
    const int d0 = v0 >> 14;
    const int wm = w0 + mi;

    // B fragments (prebuilt layout): one b128 load per step
    bf16x8 bf[7];
#pragma unroll
    for (int s = 0; s < 7; ++s)
        bf[s] = *(const bf16x8*)(w2frag + (size_t)(s * 64 + lane) * 8);

    // A pointers per step (boundary -> zeropage; padded tap 27 has B=0, clamp addr)
    const u16* ap[7];
#pragma unroll
    for (int s = 0; s < 7; ++s) {
        int tap = s * 4 + q;
        if (tap > 26) tap = 26;
        const int dz = tap / 9;
        const int dy = (tap - dz * 9) / 3;
        const int dx = tap - dz * 9 - dy * 3;
        const int za = d0 + dz - 1;
        const int ya = h0 + dy - 1;
        const int xa = wm + dx - 1;
        const bool ok = ((unsigned)za < 128u) && ((unsigned)ya < 128u) && ((unsigned)xa < 128u);
        const long off = (long)((za * 128 + ya) * 128 + xa) * 8;
        ap[s] = ok ? (x1 + off) : zeropage;
    }

    f32x4 acc = {0.f, 0.f, 0.f, 0.f};
#pragma unroll
    for (int s = 0; s < 7; ++s) {
        bf16x8 a = *(const bf16x8*)ap[s];
        acc = __builtin_amdgcn_mfma_f32_16x16x32_bf16(a, bf[s], acc, 0, 0, 0);
    }

    // C/D layout: col(oc)=lane&15, row(m)=(lane>>4)*4+reg
    const float bias = b2[mi];
    u16* outp = x2 + (((size_t)(v0 + q * 4)) << 4) + mi;
#pragma unroll
    for (int r = 0; r < 4; ++r) {
        float v = acc[r] + bias;
        v = v > 0.f ? v : 0.f;
        outp[(size_t)r << 4] = f2bf(v);
    }
}

// conv3: x2 channels-last [VOX][16] bf16 -> out fp32 (one batch), tanh.
// Per tap: 2 x b128 loads (16 ic), 16 FMAs against uniform (scalar) weights.
__global__ __launch_bounds__(256) void conv3_kernel(
    const u16* __restrict__ x2, const float* __restrict__ w3t,
    const float* __restrict__ b3, float* __restrict__ out,
    const u16* __restrict__ zeropage) {
    const int w = threadIdx.x & 127;
    const int h = (blockIdx.x << 1) | (threadIdx.x >> 7);
    const int d = blockIdx.y;

    float a0 = b3[0], a1 = 0.f, a2 = 0.f, a3 = 0.f;

#pragma unroll
    for (int dz = 0; dz < 3; ++dz) {
        const int zz = d + dz - 1;
        const bool zok = (unsigned)zz < DD;
#pragma unroll
        for (int dy = 0; dy < 3; ++dy) {
            const int yy = h + dy - 1;
            const bool yok = zok && ((unsigned)yy < HH);
#pragma unroll
            for (int dx = 0; dx < 3; ++dx) {
                const int xx = w + dx - 1;
                const bool ok = yok && ((unsigned)xx < WW);
                const long off = (long)((zz * HH + yy) * WW + xx) << 4;
                const u16* p = ok ? (x2 + off) : zeropage;
                const uint4 lo = *(const uint4*)p;
                const uint4 hi = *((const uint4*)p + 1);
                const float* wp = w3t + (dz * 9 + dy * 3 + dx) * 16;
                a0 = fmaf(wp[0], blo(lo.x), a0);
                a1 = fmaf(wp[1], bhi(lo.x), a1);
                a2 = fmaf(wp[2], blo(lo.y), a2);
                a3 = fmaf(wp[3], bhi(lo.y), a3);
                a0 = fmaf(wp[4], blo(lo.z), a0);
                a1 = fmaf(wp[5], bhi(lo.z), a1);
                a2 = fmaf(wp[6], blo(lo.w), a2);
                a3 = fmaf(wp[7], bhi(lo.w), a3);
                a0 = fmaf(wp[8], blo(hi.x), a0);
                a1 = fmaf(wp[9], bhi(hi.x), a1);
                a2 = fmaf(wp[10], blo(hi.y), a2);
                a3 = fmaf(wp[11], bhi(hi.y), a3);
                a0 = fmaf(wp[12], blo(hi.z), a0);
                a1 = fmaf(wp[13], bhi(hi.z), a1);
                a2 = fmaf(wp[14], blo(hi.w), a2);
                a3 = fmaf(wp[15], bhi(hi.w), a3);
            }
        }
    }
    const size_t voxel = (size_t)(d * HH + h) * WW + w;
    out[voxel] = tanhf((a0 + a1) + (a2 + a3));
}

extern "C" void kernel_launch(void* const* d_in, const int* in_sizes, int n_in,
                              void* d_out, int out_size, void* d_ws, size_t ws_size,
                              hipStream_t stream) {
    const float* cube = (const float*)d_in[0];
    const float* w1 = (const float*)d_in[1];
    const float* b1 = (const float*)d_in[2];
    const float* w2 = (const float*)d_in[3];
    const float* b2 = (const float*)d_in[4];
    const float* w3 = (const float*)d_in[5];
    const float* b3 = (const float*)d_in[6];
    float* out = (float*)d_out;

    // ws: zeropage 64B | w2frag 7168B | w3t 1728B | x1 32MiB | x2 64MiB  (~96 MiB)
    char* ws = (char*)d_ws;
    u16* zeropage = (u16*)ws;
    u16* w2frag = (u16*)(ws + 64);
    float* w3t = (float*)(ws + 64 + 7168);
    u16* x1 = (u16*)(ws + 16384);
    u16* x2 = (u16*)(ws + 16384 + (size_t)8 * VOX * sizeof(u16));

    prep_kernel<<<dim3(14), dim3(256), 0, stream>>>(w2, w3, w2frag, w3t, zeropage);

    dim3 grid(HH / 2, DD);
    for (int b = 0; b < 2; ++b) {
        conv1_kernel<<<grid, dim3(256), 0, stream>>>(cube + (size_t)b * VOX, w1, b1, x1);
        conv2_mfma_kernel<<<dim3(VOX / 64), dim3(256), 0, stream>>>(x1, w2frag, b2, x2, zeropage);
        conv3_kernel<<<grid, dim3(256), 0, stream>>>(x2, w3t, b3, out + (size_t)b * VOX, zeropage);
    }
}